// Round 1
// baseline (189.429 us; speedup 1.0000x reference)
//
#include <hip/hip_runtime.h>
#include <hip/hip_bf16.h>
#include <math.h>

// Problem: B=32, T=256, C=128, TNEI=2 -> NEIGH=5, TOPK=4.
// Pipeline:
//   pf = norm(x@Wpf^T), ns = norm(x@Wns^T), v = x@Wv^T          (proj_kernel)
//   Q[b,x] = sum_n w_ns[n]*ns[b, inxs[b,x,n]]                   (gather_q)
//   G[b] = pf[b]@pf[b]^T        (gemm_nt)
//   S[b] = Q[b]@ns[b]^T         (gemm_nt)
//   logits[b,x,y] = sum_i w_pf[i]*max_j G[b,sx+i,sy+j] + S[b,x,y] + mask
//   attn = softmax_y(logits)    (logits_softmax; in-place over S)
//   out[b] = attn[b]@v[b]       (pv_gemm)
// ws needed: 8M floats = 32MB.

#define TT 256
#define CC 128

__device__ __forceinline__ float brmax(float v, volatile float* red) {
    for (int o = 32; o; o >>= 1) v = fmaxf(v, __shfl_xor(v, o));
    __syncthreads();
    if ((threadIdx.x & 63) == 0) red[threadIdx.x >> 6] = v;
    __syncthreads();
    return fmaxf(fmaxf(red[0], red[1]), fmaxf(red[2], red[3]));
}
__device__ __forceinline__ float brsum(float v, volatile float* red) {
    for (int o = 32; o; o >>= 1) v += __shfl_xor(v, o);
    __syncthreads();
    if ((threadIdx.x & 63) == 0) red[threadIdx.x >> 6] = v;
    __syncthreads();
    return red[0] + red[1] + red[2] + red[3];
}

// ---- proj: 32 rows/block, 128 cols, 3 matrices. out[r][j] = sum_k x[r][k]*W[j][k]
__global__ __launch_bounds__(256) void proj_kernel(
    const float* __restrict__ x,
    const float* __restrict__ W0, const float* __restrict__ W1, const float* __restrict__ W2,
    float* __restrict__ o0, float* __restrict__ o1, float* __restrict__ o2)
{
    __shared__ float xs[32][33];
    __shared__ float Ws[128][33];
    const int tid = threadIdx.x, ty = tid >> 4, tx = tid & 15;
    const int row0 = blockIdx.x * 32;
    float acc[3][2][8];
    for (int m = 0; m < 3; m++) for (int u = 0; u < 2; u++) for (int w = 0; w < 8; w++) acc[m][u][w] = 0.f;

    for (int k0 = 0; k0 < CC; k0 += 32) {
        for (int m = 0; m < 3; m++) {
            const float* W = (m == 0) ? W0 : (m == 1) ? W1 : W2;
            __syncthreads();
            if (m == 0) {
                for (int i = 0; i < 4; i++) {
                    int flat = i * 256 + tid, r = flat >> 5, kk = flat & 31;
                    xs[r][kk] = x[(row0 + r) * CC + k0 + kk];
                }
            }
            for (int i = 0; i < 16; i++) {
                int flat = i * 256 + tid, r = flat >> 5, kk = flat & 31;
                Ws[r][kk] = W[r * CC + k0 + kk];
            }
            __syncthreads();
            for (int kk = 0; kk < 32; kk++) {
                float av[2], bv[8];
                for (int u = 0; u < 2; u++) av[u] = xs[ty + 16 * u][kk];
                for (int w = 0; w < 8; w++) bv[w] = Ws[tx + 16 * w][kk];
                for (int u = 0; u < 2; u++)
                    for (int w = 0; w < 8; w++)
                        acc[m][u][w] = fmaf(av[u], bv[w], acc[m][u][w]);
            }
        }
    }
    // normalize m=0,1 rows; m=2 raw
    for (int m = 0; m < 3; m++) {
        float* o = (m == 0) ? o0 : (m == 1) ? o1 : o2;
        for (int u = 0; u < 2; u++) {
            float inv = 1.f;
            if (m < 2) {
                float ss = 0.f;
                for (int w = 0; w < 8; w++) ss += acc[m][u][w] * acc[m][u][w];
                for (int o2_ = 8; o2_; o2_ >>= 1) ss += __shfl_xor(ss, o2_);
                inv = 1.f / fmaxf(sqrtf(ss), 1e-12f);
            }
            int row = row0 + ty + 16 * u;
            for (int w = 0; w < 8; w++)
                o[row * CC + tx + 16 * w] = acc[m][u][w] * inv;
        }
    }
}

// ---- Q[b,x,c] = sum_n w_ns[n] * ns[b, inxs[b,x,n], c]
__global__ __launch_bounds__(256) void gather_q(
    const float* __restrict__ ns, const int* __restrict__ inxs,
    const float* __restrict__ v_ns, const float* __restrict__ g_ns,
    float* __restrict__ Q)
{
    int t = blockIdx.x * 256 + threadIdx.x;   // over 8192*128
    int c = t & 127, row = t >> 7, b = row >> 8;
    float n2 = 0.f;
    for (int n = 0; n < 4; n++) n2 += v_ns[n] * v_ns[n];
    float sc = g_ns[0] / sqrtf(n2);
    float acc = 0.f;
    for (int n = 0; n < 4; n++) {
        int idx = inxs[row * 4 + n];
        acc = fmaf(v_ns[n], ns[(b * TT + idx) * CC + c], acc);
    }
    Q[t] = sc * acc;
}

// ---- C[b,m,n] = sum_k A[b,m,k]*B[b,n,k]; M=N=256,K=128; 64x64 tile
__global__ __launch_bounds__(256) void gemm_nt(
    const float* __restrict__ A, const float* __restrict__ B, float* __restrict__ C)
{
    __shared__ float As[64][33], Bs[64][33];
    const int tid = threadIdx.x, ty = tid >> 4, tx = tid & 15;
    const int m0 = blockIdx.x * 64, n0 = blockIdx.y * 64, b = blockIdx.z;
    const float* Ab = A + b * TT * CC;
    const float* Bb = B + b * TT * CC;
    float acc[4][4] = {};
    for (int k0 = 0; k0 < CC; k0 += 32) {
        __syncthreads();
        for (int i = 0; i < 8; i++) {
            int flat = i * 256 + tid, r = flat >> 5, kk = flat & 31;
            As[r][kk] = Ab[(m0 + r) * CC + k0 + kk];
            Bs[r][kk] = Bb[(n0 + r) * CC + k0 + kk];
        }
        __syncthreads();
        for (int kk = 0; kk < 32; kk++) {
            float av[4], bv[4];
            for (int u = 0; u < 4; u++) av[u] = As[ty + 16 * u][kk];
            for (int w = 0; w < 4; w++) bv[w] = Bs[tx + 16 * w][kk];
            for (int u = 0; u < 4; u++)
                for (int w = 0; w < 4; w++)
                    acc[u][w] = fmaf(av[u], bv[w], acc[u][w]);
        }
    }
    float* Cb = C + b * TT * TT;
    for (int u = 0; u < 4; u++)
        for (int w = 0; w < 4; w++)
            Cb[(m0 + ty + 16 * u) * TT + n0 + tx + 16 * w] = acc[u][w];
}

// ---- logits + softmax, in-place over S. block: (xt, b); 16 queries x 256 keys.
__global__ __launch_bounds__(256) void logits_softmax(
    const float* __restrict__ G, float* __restrict__ S, const int* __restrict__ radj,
    const float* __restrict__ v_pf, const float* __restrict__ g_pf)
{
    __shared__ float Gs[20 * 256];
    __shared__ float red[4];
    const int tid = threadIdx.x;
    const int xt = blockIdx.x, b = blockIdx.y;
    const int x0 = xt * 16;
    const int rbase = min(max(x0 - 2, 0), TT - 5);
    for (int i = 0; i < 20; i++) {
        int r = min(rbase + i, TT - 1);
        Gs[i * 256 + tid] = G[b * TT * TT + r * TT + tid];
    }
    float n2 = 0.f;
    for (int i = 0; i < 5; i++) n2 += v_pf[i] * v_pf[i];
    float sc = g_pf[0] / sqrtf(n2);
    float wpf[5];
    for (int i = 0; i < 5; i++) wpf[i] = sc * v_pf[i];
    __syncthreads();

    const int y = tid;
    const int sy = min(max(y - 2, 0), TT - 5);
    float lv[16];
    for (int xi = 0; xi < 16; xi++) {
        int gx = x0 + xi;
        int sx = min(max(gx - 2, 0), TT - 5);
        float s = 0.f;
        for (int i = 0; i < 5; i++) {
            const float* row = Gs + (sx - rbase + i) * 256 + sy;
            float mx = row[0];
            for (int j = 1; j < 5; j++) mx = fmaxf(mx, row[j]);
            s = fmaf(wpf[i], mx, s);
        }
        s += S[b * TT * TT + gx * TT + y];
        if (radj[(b * TT + gx) * TT + y] == 0) s += -1e22f;
        lv[xi] = s;
    }
    for (int xi = 0; xi < 16; xi++) {
        int gx = x0 + xi;
        float mx = brmax(lv[xi], red);
        float e = expf(lv[xi] - mx);
        float sm = brsum(e, red);
        S[b * TT * TT + gx * TT + y] = e / sm;
    }
}

// ---- out[b] = attn[b] @ v[b]; M=256 (32/block), N=128, K=256
__global__ __launch_bounds__(256) void pv_gemm(
    const float* __restrict__ attn, const float* __restrict__ V, float* __restrict__ out)
{
    __shared__ float As[32][33];
    __shared__ float Bs[32][128];
    const int tid = threadIdx.x, ty = tid >> 4, tx = tid & 15;
    const int m0 = blockIdx.x * 32, b = blockIdx.y;
    const float* Ab = attn + b * TT * TT;
    const float* Vb = V + b * TT * CC;
    float acc[2][8] = {};
    for (int k0 = 0; k0 < TT; k0 += 32) {
        __syncthreads();
        for (int i = 0; i < 4; i++) {
            int flat = i * 256 + tid, r = flat >> 5, kk = flat & 31;
            As[r][kk] = Ab[(m0 + r) * TT + k0 + kk];
        }
        for (int i = 0; i < 16; i++) {
            int flat = i * 256 + tid, kk = flat >> 7, n = flat & 127;
            Bs[kk][n] = Vb[(k0 + kk) * CC + n];
        }
        __syncthreads();
        for (int kk = 0; kk < 32; kk++) {
            float av[2];
            for (int u = 0; u < 2; u++) av[u] = As[ty + 16 * u][kk];
            for (int w = 0; w < 8; w++) {
                float bv = Bs[kk][tx + 16 * w];
                for (int u = 0; u < 2; u++)
                    acc[u][w] = fmaf(av[u], bv, acc[u][w]);
            }
        }
    }
    for (int u = 0; u < 2; u++)
        for (int w = 0; w < 8; w++)
            out[b * TT * CC + (m0 + ty + 16 * u) * CC + tx + 16 * w] = acc[u][w];
}

extern "C" void kernel_launch(void* const* d_in, const int* in_sizes, int n_in,
                              void* d_out, int out_size, void* d_ws, size_t ws_size,
                              hipStream_t stream) {
    const float* x    = (const float*)d_in[0];
    const int*   radj = (const int*)d_in[1];
    const int*   inxs = (const int*)d_in[2];
    const float* Wpf  = (const float*)d_in[3];
    const float* Wns  = (const float*)d_in[4];
    const float* Wv   = (const float*)d_in[5];
    const float* v_pf = (const float*)d_in[6];
    const float* g_pf = (const float*)d_in[7];
    const float* v_ns = (const float*)d_in[8];
    const float* g_ns = (const float*)d_in[9];
    float* out = (float*)d_out;

    float* ws = (float*)d_ws;
    float* pf = ws;                       // 1M floats
    float* ns = ws + (1u << 20);          // 1M
    float* vv = ws + 2u * (1u << 20);     // 1M
    float* Q  = ws + 3u * (1u << 20);     // 1M
    float* G  = ws + 4u * (1u << 20);     // 2M
    float* S  = ws + 6u * (1u << 20);     // 2M  (sim_ns -> attn in-place)

    proj_kernel<<<256, 256, 0, stream>>>(x, Wpf, Wns, Wv, pf, ns, vv);
    gather_q<<<4096, 256, 0, stream>>>(ns, inxs, v_ns, g_ns, Q);
    gemm_nt<<<dim3(4, 4, 32), 256, 0, stream>>>(pf, pf, G);
    gemm_nt<<<dim3(4, 4, 32), 256, 0, stream>>>(Q, ns, S);
    logits_softmax<<<dim3(16, 32), 256, 0, stream>>>(G, S, radj, v_pf, g_pf);
    pv_gemm<<<dim3(8, 32), 256, 0, stream>>>(S, vv, out);
}

// Round 2
// 164.420 us; speedup vs baseline: 1.1521x; 1.1521x over previous
//
#include <hip/hip_runtime.h>
#include <hip/hip_bf16.h>
#include <math.h>

// B=32, T=256, C=128, NEIGH=5, TOPK=4.
// pf=norm(x@Wpf^T), ns=norm(x@Wns^T), v=x@Wv^T         (proj_kernel, grid 256x3)
// Q[b,x] = sum_n w_ns[n]*ns[b,inxs[b,x,n]]             (gather_q)
// G[b]=pf[b]@pf[b]^T ; S[b]=Q[b]@ns[b]^T               (gemm_nt x2)
// logits = window-max(G)*w_pf + S + mask; softmax      (logits_softmax, 3 barriers)
// out[b] = attn[b]@v[b]                                (pv_gemm)

#define TT 256
#define CC 128

// ---- proj: 32 rows/block, one matrix per blockIdx.y. out[r][j]=sum_k x[r][k]*W[j][k]
__global__ __launch_bounds__(256) void proj_kernel(
    const float* __restrict__ x,
    const float* __restrict__ W0, const float* __restrict__ W1, const float* __restrict__ W2,
    float* __restrict__ o0, float* __restrict__ o1, float* __restrict__ o2)
{
    __shared__ float xs[32][36];   // pad 36: 144B row stride, 16B-aligned float4
    __shared__ float Ws[128][36];
    const int tid = threadIdx.x, ty = tid >> 4, tx = tid & 15;
    const int row0 = blockIdx.x * 32;
    const int m = blockIdx.y;
    const float* __restrict__ W = (m == 0) ? W0 : (m == 1) ? W1 : W2;
    float* __restrict__ o = (m == 0) ? o0 : (m == 1) ? o1 : o2;
    float acc[2][8] = {};

    for (int k0 = 0; k0 < CC; k0 += 32) {
        __syncthreads();
        {   // xs: 32x32 = 256 float4, 1/thread
            int r = tid >> 3, q = (tid & 7) * 4;
            *(float4*)&xs[r][q] = *(const float4*)&x[(row0 + r) * CC + k0 + q];
        }
        for (int i = 0; i < 4; i++) {  // Ws: 128x32 = 1024 float4, 4/thread
            int flat = i * 256 + tid, r = flat >> 3, q = (flat & 7) * 4;
            *(float4*)&Ws[r][q] = *(const float4*)&W[r * CC + k0 + q];
        }
        __syncthreads();
        for (int kq = 0; kq < 32; kq += 4) {
            float4 av[2], bv[8];
            for (int u = 0; u < 2; u++) av[u] = *(float4*)&xs[ty + 16 * u][kq];
            for (int w = 0; w < 8; w++) bv[w] = *(float4*)&Ws[tx + 16 * w][kq];
            for (int u = 0; u < 2; u++)
                for (int w = 0; w < 8; w++) {
                    acc[u][w] = fmaf(av[u].x, bv[w].x, acc[u][w]);
                    acc[u][w] = fmaf(av[u].y, bv[w].y, acc[u][w]);
                    acc[u][w] = fmaf(av[u].z, bv[w].z, acc[u][w]);
                    acc[u][w] = fmaf(av[u].w, bv[w].w, acc[u][w]);
                }
        }
    }
    for (int u = 0; u < 2; u++) {
        float inv = 1.f;
        if (m < 2) {  // row L2-normalize: reduce over the 16 tx lanes (8 cols each)
            float ss = 0.f;
            for (int w = 0; w < 8; w++) ss += acc[u][w] * acc[u][w];
            for (int off = 8; off; off >>= 1) ss += __shfl_xor(ss, off);
            inv = 1.f / fmaxf(sqrtf(ss), 1e-12f);
        }
        int row = row0 + ty + 16 * u;
        for (int w = 0; w < 8; w++)
            o[row * CC + tx + 16 * w] = acc[u][w] * inv;
    }
}

// ---- Q[b,x,c] = scale * sum_n v_ns[n] * ns[b, inxs[b,x,n], c]
__global__ __launch_bounds__(256) void gather_q(
    const float* __restrict__ ns, const int* __restrict__ inxs,
    const float* __restrict__ v_ns, const float* __restrict__ g_ns,
    float* __restrict__ Q)
{
    int t = blockIdx.x * 256 + threadIdx.x;
    int c = t & 127, row = t >> 7, b = row >> 8;
    float n2 = 0.f;
    for (int n = 0; n < 4; n++) n2 += v_ns[n] * v_ns[n];
    float sc = g_ns[0] / sqrtf(n2);
    float acc = 0.f;
    for (int n = 0; n < 4; n++) {
        int idx = inxs[row * 4 + n];
        acc = fmaf(v_ns[n], ns[(b * TT + idx) * CC + c], acc);
    }
    Q[t] = sc * acc;
}

// ---- C[b,m,n] = sum_k A[b,m,k]*B[b,n,k]; M=N=256,K=128; 64x64 tile, float4 LDS
__global__ __launch_bounds__(256) void gemm_nt(
    const float* __restrict__ A, const float* __restrict__ B, float* __restrict__ C)
{
    __shared__ float As[64][36], Bs[64][36];
    const int tid = threadIdx.x, ty = tid >> 4, tx = tid & 15;
    const int m0 = blockIdx.x * 64, n0 = blockIdx.y * 64, b = blockIdx.z;
    const float* __restrict__ Ab = A + b * TT * CC;
    const float* __restrict__ Bb = B + b * TT * CC;
    float acc[4][4] = {};
    for (int k0 = 0; k0 < CC; k0 += 32) {
        __syncthreads();
        for (int i = 0; i < 2; i++) {  // 64x32 = 512 float4 each, 2/thread
            int flat = i * 256 + tid, r = flat >> 3, q = (flat & 7) * 4;
            *(float4*)&As[r][q] = *(const float4*)&Ab[(m0 + r) * CC + k0 + q];
            *(float4*)&Bs[r][q] = *(const float4*)&Bb[(n0 + r) * CC + k0 + q];
        }
        __syncthreads();
        for (int kq = 0; kq < 32; kq += 4) {
            float4 av[4], bv[4];
            for (int u = 0; u < 4; u++) av[u] = *(float4*)&As[ty + 16 * u][kq];
            for (int w = 0; w < 4; w++) bv[w] = *(float4*)&Bs[tx + 16 * w][kq];
            for (int u = 0; u < 4; u++)
                for (int w = 0; w < 4; w++) {
                    acc[u][w] = fmaf(av[u].x, bv[w].x, acc[u][w]);
                    acc[u][w] = fmaf(av[u].y, bv[w].y, acc[u][w]);
                    acc[u][w] = fmaf(av[u].z, bv[w].z, acc[u][w]);
                    acc[u][w] = fmaf(av[u].w, bv[w].w, acc[u][w]);
                }
        }
    }
    float* __restrict__ Cb = C + b * TT * TT;
    for (int u = 0; u < 4; u++)
        for (int w = 0; w < 4; w++)
            Cb[(m0 + ty + 16 * u) * TT + n0 + tx + 16 * w] = acc[u][w];
}

// ---- logits + softmax, in-place over S. block: 16 queries x 256 keys; 3 barriers.
__global__ __launch_bounds__(256) void logits_softmax(
    const float* __restrict__ G, float* __restrict__ S, const int* __restrict__ radj,
    const float* __restrict__ v_pf, const float* __restrict__ g_pf)
{
    __shared__ float Gs[20 * 256];
    __shared__ float redm[16][4];
    __shared__ float reds[16][4];
    const int tid = threadIdx.x;
    const int xt = blockIdx.x, b = blockIdx.y;
    const int x0 = xt * 16;
    const int rbase = min(max(x0 - 2, 0), TT - 5);
    for (int i = 0; i < 20; i++) {
        int r = min(rbase + i, TT - 1);
        Gs[i * 256 + tid] = G[b * TT * TT + r * TT + tid];
    }
    float n2 = 0.f;
    for (int i = 0; i < 5; i++) n2 += v_pf[i] * v_pf[i];
    float sc = g_pf[0] / sqrtf(n2);
    float wpf[5];
    for (int i = 0; i < 5; i++) wpf[i] = sc * v_pf[i];
    __syncthreads();

    const int y = tid;
    const int sy = min(max(y - 2, 0), TT - 5);
    float lv[16];
    for (int xi = 0; xi < 16; xi++) {
        int gx = x0 + xi;
        int sx = min(max(gx - 2, 0), TT - 5);
        float s = 0.f;
        for (int i = 0; i < 5; i++) {
            const float* row = Gs + (sx - rbase + i) * 256 + sy;
            float mx = row[0];
            for (int j = 1; j < 5; j++) mx = fmaxf(mx, row[j]);
            s = fmaf(wpf[i], mx, s);
        }
        s += S[b * TT * TT + gx * TT + y];
        if (radj[(b * TT + gx) * TT + y] == 0) s += -1e22f;
        lv[xi] = s;
    }
    const int lane = tid & 63, wv = tid >> 6;
    for (int xi = 0; xi < 16; xi++) {
        float v = lv[xi];
        for (int o = 32; o; o >>= 1) v = fmaxf(v, __shfl_xor(v, o));
        if (lane == 0) redm[xi][wv] = v;
    }
    __syncthreads();
    float ev[16];
    for (int xi = 0; xi < 16; xi++) {
        float mx = fmaxf(fmaxf(redm[xi][0], redm[xi][1]), fmaxf(redm[xi][2], redm[xi][3]));
        float e = __expf(lv[xi] - mx);
        ev[xi] = e;
        for (int o = 32; o; o >>= 1) e += __shfl_xor(e, o);
        if (lane == 0) reds[xi][wv] = e;
    }
    __syncthreads();
    for (int xi = 0; xi < 16; xi++) {
        float sm = reds[xi][0] + reds[xi][1] + reds[xi][2] + reds[xi][3];
        S[b * TT * TT + (x0 + xi) * TT + y] = ev[xi] / sm;
    }
}

// ---- out[b] = attn[b] @ v[b]; M=256 (32/block), N=128, K=256
__global__ __launch_bounds__(256) void pv_gemm(
    const float* __restrict__ attn, const float* __restrict__ V, float* __restrict__ out)
{
    __shared__ float As[32][33];
    __shared__ float Bs[32][128];
    const int tid = threadIdx.x, ty = tid >> 4, tx = tid & 15;
    const int m0 = blockIdx.x * 32, b = blockIdx.y;
    const float* __restrict__ Ab = attn + b * TT * TT;
    const float* __restrict__ Vb = V + b * TT * CC;
    float acc[2][8] = {};
    for (int k0 = 0; k0 < TT; k0 += 32) {
        __syncthreads();
        for (int i = 0; i < 4; i++) {
            int flat = i * 256 + tid, r = flat >> 5, kk = flat & 31;
            As[r][kk] = Ab[(m0 + r) * TT + k0 + kk];
        }
        for (int i = 0; i < 16; i++) {
            int flat = i * 256 + tid, kk = flat >> 7, n = flat & 127;
            Bs[kk][n] = Vb[(k0 + kk) * CC + n];
        }
        __syncthreads();
        for (int kk = 0; kk < 32; kk++) {
            float av[2];
            for (int u = 0; u < 2; u++) av[u] = As[ty + 16 * u][kk];
            for (int w = 0; w < 8; w++) {
                float bv = Bs[kk][tx + 16 * w];
                for (int u = 0; u < 2; u++)
                    acc[u][w] = fmaf(av[u], bv, acc[u][w]);
            }
        }
    }
    for (int u = 0; u < 2; u++)
        for (int w = 0; w < 8; w++)
            out[b * TT * CC + (m0 + ty + 16 * u) * CC + tx + 16 * w] = acc[u][w];
}

extern "C" void kernel_launch(void* const* d_in, const int* in_sizes, int n_in,
                              void* d_out, int out_size, void* d_ws, size_t ws_size,
                              hipStream_t stream) {
    const float* x    = (const float*)d_in[0];
    const int*   radj = (const int*)d_in[1];
    const int*   inxs = (const int*)d_in[2];
    const float* Wpf  = (const float*)d_in[3];
    const float* Wns  = (const float*)d_in[4];
    const float* Wv   = (const float*)d_in[5];
    const float* v_pf = (const float*)d_in[6];
    const float* g_pf = (const float*)d_in[7];
    const float* v_ns = (const float*)d_in[8];
    const float* g_ns = (const float*)d_in[9];
    float* out = (float*)d_out;

    float* ws = (float*)d_ws;
    float* pf = ws;                       // 1M floats
    float* ns = ws + (1u << 20);          // 1M
    float* vv = ws + 2u * (1u << 20);     // 1M
    float* Q  = ws + 3u * (1u << 20);     // 1M
    float* G  = ws + 4u * (1u << 20);     // 2M
    float* S  = ws + 6u * (1u << 20);     // 2M (sim_ns -> attn in-place)

    proj_kernel<<<dim3(256, 3), 256, 0, stream>>>(x, Wpf, Wns, Wv, pf, ns, vv);
    gather_q<<<4096, 256, 0, stream>>>(ns, inxs, v_ns, g_ns, Q);
    gemm_nt<<<dim3(4, 4, 32), 256, 0, stream>>>(pf, pf, G);
    gemm_nt<<<dim3(4, 4, 32), 256, 0, stream>>>(Q, ns, S);
    logits_softmax<<<dim3(16, 32), 256, 0, stream>>>(G, S, radj, v_pf, g_pf);
    pv_gemm<<<dim3(8, 32), 256, 0, stream>>>(S, vv, out);
}

// Round 3
// 158.260 us; speedup vs baseline: 1.1970x; 1.0389x over previous
//
#include <hip/hip_runtime.h>
#include <hip/hip_bf16.h>
#include <math.h>

// B=32, T=256, C=128, NEIGH=5, TOPK=4.
// pf=norm(x@Wpf^T), ns=norm(x@Wns^T), v=x@Wv^T         (proj_kernel, grid 256x3)
// G[b]=pf[b]@pf[b]^T                                   (gram_pf)
// S[b]=Q[b]@ns[b]^T, Q gathered+weighted on the fly    (gram_ns, fused gather)
// logits = window-max(G)*w_pf + S + mask; softmax      (logits_softmax)
// out[b] = attn[b]@v[b]                                (pv_gemm)

#define TT 256
#define CC 128

// ---- proj: 32 rows/block, one matrix per blockIdx.y. out[r][j]=sum_k x[r][k]*W[j][k]
__global__ __launch_bounds__(256) void proj_kernel(
    const float* __restrict__ x,
    const float* __restrict__ W0, const float* __restrict__ W1, const float* __restrict__ W2,
    float* __restrict__ o0, float* __restrict__ o1, float* __restrict__ o2)
{
    __shared__ float xs[32][36];
    __shared__ float Ws[128][36];
    const int tid = threadIdx.x, ty = tid >> 4, tx = tid & 15;
    const int row0 = blockIdx.x * 32;
    const int m = blockIdx.y;
    const float* __restrict__ W = (m == 0) ? W0 : (m == 1) ? W1 : W2;
    float* __restrict__ o = (m == 0) ? o0 : (m == 1) ? o1 : o2;
    float acc[2][8] = {};

    for (int k0 = 0; k0 < CC; k0 += 32) {
        __syncthreads();
        {
            int r = tid >> 3, q = (tid & 7) * 4;
            *(float4*)&xs[r][q] = *(const float4*)&x[(row0 + r) * CC + k0 + q];
        }
        for (int i = 0; i < 4; i++) {
            int flat = i * 256 + tid, r = flat >> 3, q = (flat & 7) * 4;
            *(float4*)&Ws[r][q] = *(const float4*)&W[r * CC + k0 + q];
        }
        __syncthreads();
        for (int kq = 0; kq < 32; kq += 4) {
            float4 av[2], bv[8];
            for (int u = 0; u < 2; u++) av[u] = *(float4*)&xs[ty + 16 * u][kq];
            for (int w = 0; w < 8; w++) bv[w] = *(float4*)&Ws[tx + 16 * w][kq];
            for (int u = 0; u < 2; u++)
                for (int w = 0; w < 8; w++) {
                    acc[u][w] = fmaf(av[u].x, bv[w].x, acc[u][w]);
                    acc[u][w] = fmaf(av[u].y, bv[w].y, acc[u][w]);
                    acc[u][w] = fmaf(av[u].z, bv[w].z, acc[u][w]);
                    acc[u][w] = fmaf(av[u].w, bv[w].w, acc[u][w]);
                }
        }
    }
    for (int u = 0; u < 2; u++) {
        float inv = 1.f;
        if (m < 2) {
            float ss = 0.f;
            for (int w = 0; w < 8; w++) ss += acc[u][w] * acc[u][w];
            for (int off = 8; off; off >>= 1) ss += __shfl_xor(ss, off);
            inv = 1.f / fmaxf(sqrtf(ss), 1e-12f);
        }
        int row = row0 + ty + 16 * u;
        for (int w = 0; w < 8; w++)
            o[row * CC + tx + 16 * w] = acc[u][w] * inv;
    }
}

// ---- G[b,m,n] = sum_k pf[b,m,k]*pf[b,n,k]; 64x64 tile
__global__ __launch_bounds__(256) void gram_pf(
    const float* __restrict__ A, float* __restrict__ C)
{
    __shared__ float As[64][36], Bs[64][36];
    const int tid = threadIdx.x, ty = tid >> 4, tx = tid & 15;
    const int m0 = blockIdx.x * 64, n0 = blockIdx.y * 64, b = blockIdx.z;
    const float* __restrict__ Ab = A + b * TT * CC;
    float acc[4][4] = {};
    for (int k0 = 0; k0 < CC; k0 += 32) {
        __syncthreads();
        for (int i = 0; i < 2; i++) {
            int flat = i * 256 + tid, r = flat >> 3, q = (flat & 7) * 4;
            *(float4*)&As[r][q] = *(const float4*)&Ab[(m0 + r) * CC + k0 + q];
            *(float4*)&Bs[r][q] = *(const float4*)&Ab[(n0 + r) * CC + k0 + q];
        }
        __syncthreads();
        for (int kq = 0; kq < 32; kq += 4) {
            float4 av[4], bv[4];
            for (int u = 0; u < 4; u++) av[u] = *(float4*)&As[ty + 16 * u][kq];
            for (int w = 0; w < 4; w++) bv[w] = *(float4*)&Bs[tx + 16 * w][kq];
            for (int u = 0; u < 4; u++)
                for (int w = 0; w < 4; w++) {
                    acc[u][w] = fmaf(av[u].x, bv[w].x, acc[u][w]);
                    acc[u][w] = fmaf(av[u].y, bv[w].y, acc[u][w]);
                    acc[u][w] = fmaf(av[u].z, bv[w].z, acc[u][w]);
                    acc[u][w] = fmaf(av[u].w, bv[w].w, acc[u][w]);
                }
        }
    }
    float* __restrict__ Cb = C + b * TT * TT;
    for (int u = 0; u < 4; u++)
        for (int w = 0; w < 4; w++)
            Cb[(m0 + ty + 16 * u) * TT + n0 + tx + 16 * w] = acc[u][w];
}

// ---- S[b,m,n] = sum_k Q[b,m,k]*ns[b,n,k], Q[b,m]=sc*sum_n v_ns[n]*ns[b,inxs[b,m,n]]
__global__ __launch_bounds__(256) void gram_ns(
    const float* __restrict__ ns, const int* __restrict__ inxs,
    const float* __restrict__ v_ns, const float* __restrict__ g_ns,
    float* __restrict__ C)
{
    __shared__ float As[64][36], Bs[64][36];
    const int tid = threadIdx.x, ty = tid >> 4, tx = tid & 15;
    const int m0 = blockIdx.x * 64, n0 = blockIdx.y * 64, b = blockIdx.z;
    const float* __restrict__ Nb = ns + b * TT * CC;
    float n2 = v_ns[0]*v_ns[0] + v_ns[1]*v_ns[1] + v_ns[2]*v_ns[2] + v_ns[3]*v_ns[3];
    float sc = g_ns[0] / sqrtf(n2);
    const float w0 = sc*v_ns[0], w1 = sc*v_ns[1], w2 = sc*v_ns[2], w3 = sc*v_ns[3];
    float acc[4][4] = {};
    for (int k0 = 0; k0 < CC; k0 += 32) {
        __syncthreads();
        for (int i = 0; i < 2; i++) {
            int flat = i * 256 + tid, r = flat >> 3, q = (flat & 7) * 4;
            int4 id = *(const int4*)&inxs[(b * TT + m0 + r) * 4];
            float4 aa = *(const float4*)&Nb[id.x * CC + k0 + q];
            float4 ab = *(const float4*)&Nb[id.y * CC + k0 + q];
            float4 ac = *(const float4*)&Nb[id.z * CC + k0 + q];
            float4 ad = *(const float4*)&Nb[id.w * CC + k0 + q];
            float4 r4;
            r4.x = w0*aa.x + w1*ab.x + w2*ac.x + w3*ad.x;
            r4.y = w0*aa.y + w1*ab.y + w2*ac.y + w3*ad.y;
            r4.z = w0*aa.z + w1*ab.z + w2*ac.z + w3*ad.z;
            r4.w = w0*aa.w + w1*ab.w + w2*ac.w + w3*ad.w;
            *(float4*)&As[r][q] = r4;
            *(float4*)&Bs[r][q] = *(const float4*)&Nb[(n0 + r) * CC + k0 + q];
        }
        __syncthreads();
        for (int kq = 0; kq < 32; kq += 4) {
            float4 av[4], bv[4];
            for (int u = 0; u < 4; u++) av[u] = *(float4*)&As[ty + 16 * u][kq];
            for (int w = 0; w < 4; w++) bv[w] = *(float4*)&Bs[tx + 16 * w][kq];
            for (int u = 0; u < 4; u++)
                for (int w = 0; w < 4; w++) {
                    acc[u][w] = fmaf(av[u].x, bv[w].x, acc[u][w]);
                    acc[u][w] = fmaf(av[u].y, bv[w].y, acc[u][w]);
                    acc[u][w] = fmaf(av[u].z, bv[w].z, acc[u][w]);
                    acc[u][w] = fmaf(av[u].w, bv[w].w, acc[u][w]);
                }
        }
    }
    float* __restrict__ Cb = C + b * TT * TT;
    for (int u = 0; u < 4; u++)
        for (int w = 0; w < 4; w++)
            Cb[(m0 + ty + 16 * u) * TT + n0 + tx + 16 * w] = acc[u][w];
}

// ---- logits + softmax, in-place over S. 16 queries x 256 keys; 3 barriers.
__global__ __launch_bounds__(256) void logits_softmax(
    const float* __restrict__ G, float* __restrict__ S, const int* __restrict__ radj,
    const float* __restrict__ v_pf, const float* __restrict__ g_pf)
{
    __shared__ float Gs[20 * 256];
    __shared__ float redm[16][4];
    __shared__ float reds[16][4];
    const int tid = threadIdx.x;
    const int xt = blockIdx.x, b = blockIdx.y;
    const int x0 = xt * 16;
    const int rbase = min(max(x0 - 2, 0), TT - 5);
    for (int i = 0; i < 5; i++) {            // 20 rows x 256 = 1280 float4
        int flat = i * 256 + tid, ri = flat >> 6, q = (flat & 63) * 4;
        int r = min(rbase + ri, TT - 1);
        *(float4*)&Gs[ri * 256 + q] = *(const float4*)&G[b * TT * TT + r * TT + q];
    }
    float n2 = 0.f;
    for (int i = 0; i < 5; i++) n2 += v_pf[i] * v_pf[i];
    float sc = g_pf[0] / sqrtf(n2);
    float wpf[5];
    for (int i = 0; i < 5; i++) wpf[i] = sc * v_pf[i];
    __syncthreads();

    const int y = tid;
    const int sy = min(max(y - 2, 0), TT - 5);
    float lv[16];
    for (int xi = 0; xi < 16; xi++) {
        int gx = x0 + xi;
        int sx = min(max(gx - 2, 0), TT - 5);
        float s = 0.f;
        for (int i = 0; i < 5; i++) {
            const float* row = Gs + (sx - rbase + i) * 256 + sy;
            float mx = row[0];
            for (int j = 1; j < 5; j++) mx = fmaxf(mx, row[j]);
            s = fmaf(wpf[i], mx, s);
        }
        s += S[b * TT * TT + gx * TT + y];
        if (radj[(b * TT + gx) * TT + y] == 0) s += -1e22f;
        lv[xi] = s;
    }
    const int lane = tid & 63, wv = tid >> 6;
    for (int xi = 0; xi < 16; xi++) {
        float v = lv[xi];
        for (int o = 32; o; o >>= 1) v = fmaxf(v, __shfl_xor(v, o));
        if (lane == 0) redm[xi][wv] = v;
    }
    __syncthreads();
    float ev[16];
    for (int xi = 0; xi < 16; xi++) {
        float mx = fmaxf(fmaxf(redm[xi][0], redm[xi][1]), fmaxf(redm[xi][2], redm[xi][3]));
        float e = __expf(lv[xi] - mx);
        ev[xi] = e;
        for (int o = 32; o; o >>= 1) e += __shfl_xor(e, o);
        if (lane == 0) reds[xi][wv] = e;
    }
    __syncthreads();
    for (int xi = 0; xi < 16; xi++) {
        float sm = reds[xi][0] + reds[xi][1] + reds[xi][2] + reds[xi][3];
        S[b * TT * TT + (x0 + xi) * TT + y] = ev[xi] / sm;
    }
}

// ---- out[b] = attn[b] @ v[b]; 32 rows/block, vectorized
__global__ __launch_bounds__(256) void pv_gemm(
    const float* __restrict__ attn, const float* __restrict__ V, float* __restrict__ out)
{
    __shared__ float As[32][36];
    __shared__ float Bs[32][128];
    const int tid = threadIdx.x, ty = tid >> 4, tx = tid & 15;
    const int m0 = blockIdx.x * 32, b = blockIdx.y;
    const float* __restrict__ Ab = attn + b * TT * TT;
    const float* __restrict__ Vb = V + b * TT * CC;
    float4 acc[2][2] = {};
    for (int k0 = 0; k0 < TT; k0 += 32) {
        __syncthreads();
        {   // As: 32x32 = 256 float4, 1/thread
            int r = tid >> 3, q = (tid & 7) * 4;
            *(float4*)&As[r][q] = *(const float4*)&Ab[(m0 + r) * TT + k0 + q];
        }
        for (int i = 0; i < 4; i++) {  // Bs: 32x128 = 1024 float4, 4/thread
            int flat = i * 256 + tid, kk = flat >> 5, q = (flat & 31) * 4;
            *(float4*)&Bs[kk][q] = *(const float4*)&Vb[(k0 + kk) * CC + q];
        }
        __syncthreads();
        for (int kq = 0; kq < 32; kq += 4) {
            float4 a0 = *(float4*)&As[ty][kq];
            float4 a1 = *(float4*)&As[ty + 16][kq];
            const float ar[2][4] = {{a0.x, a0.y, a0.z, a0.w}, {a1.x, a1.y, a1.z, a1.w}};
            for (int kk = 0; kk < 4; kk++) {
                float4 b0 = *(float4*)&Bs[kq + kk][4 * tx];
                float4 b1 = *(float4*)&Bs[kq + kk][64 + 4 * tx];
                for (int u = 0; u < 2; u++) {
                    float a = ar[u][kk];
                    acc[u][0].x = fmaf(a, b0.x, acc[u][0].x);
                    acc[u][0].y = fmaf(a, b0.y, acc[u][0].y);
                    acc[u][0].z = fmaf(a, b0.z, acc[u][0].z);
                    acc[u][0].w = fmaf(a, b0.w, acc[u][0].w);
                    acc[u][1].x = fmaf(a, b1.x, acc[u][1].x);
                    acc[u][1].y = fmaf(a, b1.y, acc[u][1].y);
                    acc[u][1].z = fmaf(a, b1.z, acc[u][1].z);
                    acc[u][1].w = fmaf(a, b1.w, acc[u][1].w);
                }
            }
        }
    }
    for (int u = 0; u < 2; u++) {
        int m = m0 + ty + 16 * u;
        *(float4*)&out[b * TT * CC + m * CC + 4 * tx]      = acc[u][0];
        *(float4*)&out[b * TT * CC + m * CC + 64 + 4 * tx] = acc[u][1];
    }
}

extern "C" void kernel_launch(void* const* d_in, const int* in_sizes, int n_in,
                              void* d_out, int out_size, void* d_ws, size_t ws_size,
                              hipStream_t stream) {
    const float* x    = (const float*)d_in[0];
    const int*   radj = (const int*)d_in[1];
    const int*   inxs = (const int*)d_in[2];
    const float* Wpf  = (const float*)d_in[3];
    const float* Wns  = (const float*)d_in[4];
    const float* Wv   = (const float*)d_in[5];
    const float* v_pf = (const float*)d_in[6];
    const float* g_pf = (const float*)d_in[7];
    const float* v_ns = (const float*)d_in[8];
    const float* g_ns = (const float*)d_in[9];
    float* out = (float*)d_out;

    float* ws = (float*)d_ws;
    float* pf = ws;                       // 1M floats
    float* ns = ws + (1u << 20);          // 1M
    float* vv = ws + 2u * (1u << 20);     // 1M
    float* G  = ws + 4u * (1u << 20);     // 2M
    float* S  = ws + 6u * (1u << 20);     // 2M (sim_ns -> attn in-place)

    proj_kernel<<<dim3(256, 3), 256, 0, stream>>>(x, Wpf, Wns, Wv, pf, ns, vv);
    gram_pf<<<dim3(4, 4, 32), 256, 0, stream>>>(pf, G);
    gram_ns<<<dim3(4, 4, 32), 256, 0, stream>>>(ns, inxs, v_ns, g_ns, S);
    logits_softmax<<<dim3(16, 32), 256, 0, stream>>>(G, S, radj, v_pf, g_pf);
    pv_gemm<<<dim3(8, 32), 256, 0, stream>>>(S, vv, out);
}

// Round 4
// 149.531 us; speedup vs baseline: 1.2668x; 1.0584x over previous
//
#include <hip/hip_runtime.h>
#include <hip/hip_bf16.h>
#include <math.h>

// B=32, T=256, C=128, NEIGH=5, TOPK=4.
// proj_kernel: pf=norm(x@Wpf^T), ns=norm(x@Wns^T), v=x@Wv^T   (grid 256x3)
// gram_combined: z&1==0 -> G[b]=pf@pf^T ; z&1==1 -> S[b]=Q@ns^T (Q gathered)
// logits_softmax_pv: logits = window-max(G)*w_pf + S + mask; softmax in LDS;
//                    out = attn @ v  (attn never leaves LDS)

#define TT 256
#define CC 128

// ---- proj: 32 rows/block, one matrix per blockIdx.y.
__global__ __launch_bounds__(256) void proj_kernel(
    const float* __restrict__ x,
    const float* __restrict__ W0, const float* __restrict__ W1, const float* __restrict__ W2,
    float* __restrict__ o0, float* __restrict__ o1, float* __restrict__ o2)
{
    __shared__ float xs[32][36];
    __shared__ float Ws[128][36];
    const int tid = threadIdx.x, ty = tid >> 4, tx = tid & 15;
    const int row0 = blockIdx.x * 32;
    const int m = blockIdx.y;
    const float* __restrict__ W = (m == 0) ? W0 : (m == 1) ? W1 : W2;
    float* __restrict__ o = (m == 0) ? o0 : (m == 1) ? o1 : o2;
    float acc[2][8] = {};

    for (int k0 = 0; k0 < CC; k0 += 32) {
        __syncthreads();
        {
            int r = tid >> 3, q = (tid & 7) * 4;
            *(float4*)&xs[r][q] = *(const float4*)&x[(row0 + r) * CC + k0 + q];
        }
        for (int i = 0; i < 4; i++) {
            int flat = i * 256 + tid, r = flat >> 3, q = (flat & 7) * 4;
            *(float4*)&Ws[r][q] = *(const float4*)&W[r * CC + k0 + q];
        }
        __syncthreads();
        for (int kq = 0; kq < 32; kq += 4) {
            float4 av[2], bv[8];
            for (int u = 0; u < 2; u++) av[u] = *(float4*)&xs[ty + 16 * u][kq];
            for (int w = 0; w < 8; w++) bv[w] = *(float4*)&Ws[tx + 16 * w][kq];
            for (int u = 0; u < 2; u++)
                for (int w = 0; w < 8; w++) {
                    acc[u][w] = fmaf(av[u].x, bv[w].x, acc[u][w]);
                    acc[u][w] = fmaf(av[u].y, bv[w].y, acc[u][w]);
                    acc[u][w] = fmaf(av[u].z, bv[w].z, acc[u][w]);
                    acc[u][w] = fmaf(av[u].w, bv[w].w, acc[u][w]);
                }
        }
    }
    for (int u = 0; u < 2; u++) {
        float inv = 1.f;
        if (m < 2) {
            float ss = 0.f;
            for (int w = 0; w < 8; w++) ss += acc[u][w] * acc[u][w];
            for (int off = 8; off; off >>= 1) ss += __shfl_xor(ss, off);
            inv = 1.f / fmaxf(sqrtf(ss), 1e-12f);
        }
        int row = row0 + ty + 16 * u;
        for (int w = 0; w < 8; w++)
            o[row * CC + tx + 16 * w] = acc[u][w] * inv;
    }
}

// ---- one kernel, two Grams. z = b*2 + half. half=0: G=pf@pf^T. half=1: S=Q@ns^T.
__global__ __launch_bounds__(256, 4) void gram_combined(
    const float* __restrict__ pf, const float* __restrict__ ns,
    const int* __restrict__ inxs, const float* __restrict__ v_ns,
    const float* __restrict__ g_ns, float* __restrict__ G, float* __restrict__ S)
{
    __shared__ float As[64][36], Bs[64][36];
    const int tid = threadIdx.x, ty = tid >> 4, tx = tid & 15;
    const int m0 = blockIdx.x * 64, n0 = blockIdx.y * 64;
    const int b = blockIdx.z >> 1, half = blockIdx.z & 1;
    const float* __restrict__ Pb = pf + b * TT * CC;
    const float* __restrict__ Nb = ns + b * TT * CC;

    float w0 = 0.f, w1 = 0.f, w2 = 0.f, w3 = 0.f;
    int4 id0 = {0, 0, 0, 0}, id1 = {0, 0, 0, 0};
    if (half) {
        float n2 = v_ns[0]*v_ns[0] + v_ns[1]*v_ns[1] + v_ns[2]*v_ns[2] + v_ns[3]*v_ns[3];
        float sc = g_ns[0] / sqrtf(n2);
        w0 = sc*v_ns[0]; w1 = sc*v_ns[1]; w2 = sc*v_ns[2]; w3 = sc*v_ns[3];
        id0 = *(const int4*)&inxs[(b * TT + m0 + (tid >> 3)) * 4];
        id1 = *(const int4*)&inxs[(b * TT + m0 + 32 + (tid >> 3)) * 4];
    }

    float acc[4][4] = {};
    for (int k0 = 0; k0 < CC; k0 += 32) {
        __syncthreads();
        if (!half) {
            for (int i = 0; i < 2; i++) {
                int flat = i * 256 + tid, r = flat >> 3, q = (flat & 7) * 4;
                *(float4*)&As[r][q] = *(const float4*)&Pb[(m0 + r) * CC + k0 + q];
                *(float4*)&Bs[r][q] = *(const float4*)&Pb[(n0 + r) * CC + k0 + q];
            }
        } else {
            for (int i = 0; i < 2; i++) {
                int flat = i * 256 + tid, r = flat >> 3, q = (flat & 7) * 4;
                int4 id = i ? id1 : id0;
                float4 aa = *(const float4*)&Nb[id.x * CC + k0 + q];
                float4 ab = *(const float4*)&Nb[id.y * CC + k0 + q];
                float4 ac = *(const float4*)&Nb[id.z * CC + k0 + q];
                float4 ad = *(const float4*)&Nb[id.w * CC + k0 + q];
                float4 r4;
                r4.x = w0*aa.x + w1*ab.x + w2*ac.x + w3*ad.x;
                r4.y = w0*aa.y + w1*ab.y + w2*ac.y + w3*ad.y;
                r4.z = w0*aa.z + w1*ab.z + w2*ac.z + w3*ad.z;
                r4.w = w0*aa.w + w1*ab.w + w2*ac.w + w3*ad.w;
                *(float4*)&As[r][q] = r4;
                *(float4*)&Bs[r][q] = *(const float4*)&Nb[(n0 + r) * CC + k0 + q];
            }
        }
        __syncthreads();
        for (int kq = 0; kq < 32; kq += 4) {
            float4 av[4], bv[4];
            for (int u = 0; u < 4; u++) av[u] = *(float4*)&As[ty + 16 * u][kq];
            for (int w = 0; w < 4; w++) bv[w] = *(float4*)&Bs[tx + 16 * w][kq];
            for (int u = 0; u < 4; u++)
                for (int w = 0; w < 4; w++) {
                    acc[u][w] = fmaf(av[u].x, bv[w].x, acc[u][w]);
                    acc[u][w] = fmaf(av[u].y, bv[w].y, acc[u][w]);
                    acc[u][w] = fmaf(av[u].z, bv[w].z, acc[u][w]);
                    acc[u][w] = fmaf(av[u].w, bv[w].w, acc[u][w]);
                }
        }
    }
    float* __restrict__ Cb = (half ? S : G) + b * TT * TT;
    for (int u = 0; u < 4; u++)
        for (int w = 0; w < 4; w++)
            Cb[(m0 + ty + 16 * u) * TT + n0 + tx + 16 * w] = acc[u][w];
}

// ---- logits + softmax (attn stays in LDS) + PV. 16 queries x full key row.
__global__ __launch_bounds__(256, 4) void logits_softmax_pv(
    const float* __restrict__ G, const float* __restrict__ S,
    const int* __restrict__ radj, const float* __restrict__ v_pf,
    const float* __restrict__ g_pf, const float* __restrict__ V,
    float* __restrict__ out)
{
    __shared__ float Gs[20 * 256];       // phase 2: reused as Vs[32][132]
    __shared__ float attn[16 * 260];     // raw e; pad 260 -> bank offset 4r
    __shared__ float redm[16][4];
    __shared__ float reds[16][4];
    const int tid = threadIdx.x;
    const int xt = blockIdx.x, b = blockIdx.y;
    const int x0 = xt * 16;
    const int rbase = min(max(x0 - 2, 0), TT - 5);
    for (int i = 0; i < 5; i++) {
        int flat = i * 256 + tid, ri = flat >> 6, q = (flat & 63) * 4;
        int r = min(rbase + ri, TT - 1);
        *(float4*)&Gs[ri * 256 + q] = *(const float4*)&G[b * TT * TT + r * TT + q];
    }
    float n2 = 0.f;
    for (int i = 0; i < 5; i++) n2 += v_pf[i] * v_pf[i];
    float sc = g_pf[0] / sqrtf(n2);
    float wpf[5];
    for (int i = 0; i < 5; i++) wpf[i] = sc * v_pf[i];
    __syncthreads();

    const int y = tid;
    const int sy = min(max(y - 2, 0), TT - 5);
    float lv[16];
    for (int xi = 0; xi < 16; xi++) {
        int gx = x0 + xi;
        int sx = min(max(gx - 2, 0), TT - 5);
        float s = 0.f;
        for (int i = 0; i < 5; i++) {
            const float* row = Gs + (sx - rbase + i) * 256 + sy;
            float mx = row[0];
            for (int j = 1; j < 5; j++) mx = fmaxf(mx, row[j]);
            s = fmaf(wpf[i], mx, s);
        }
        s += S[b * TT * TT + gx * TT + y];
        if (radj[(b * TT + gx) * TT + y] == 0) s += -1e22f;
        lv[xi] = s;
    }
    const int lane = tid & 63, wv = tid >> 6;
    for (int xi = 0; xi < 16; xi++) {
        float v = lv[xi];
        for (int o = 32; o; o >>= 1) v = fmaxf(v, __shfl_xor(v, o));
        if (lane == 0) redm[xi][wv] = v;
    }
    __syncthreads();
    for (int xi = 0; xi < 16; xi++) {
        float mx = fmaxf(fmaxf(redm[xi][0], redm[xi][1]), fmaxf(redm[xi][2], redm[xi][3]));
        float e = __expf(lv[xi] - mx);
        attn[xi * 260 + y] = e;          // raw; normalized in PV epilogue
        for (int o = 32; o; o >>= 1) e += __shfl_xor(e, o);
        if (lane == 0) reds[xi][wv] = e;
    }
    // ---- phase 2: PV. Gs region becomes Vs[32][132].
    float* Vs = Gs;
    const int r = tid >> 4, tx = tid & 15;
    const float* __restrict__ Vb = V + b * TT * CC;
    float4 acc0 = {0, 0, 0, 0}, acc1 = {0, 0, 0, 0};
    for (int k0 = 0; k0 < TT; k0 += 32) {
        __syncthreads();                 // first iter: covers attn/reds/Gs-free too
        for (int i = 0; i < 4; i++) {
            int flat = i * 256 + tid, kk = flat >> 5, q = (flat & 31) * 4;
            *(float4*)&Vs[kk * 132 + q] = *(const float4*)&Vb[(k0 + kk) * CC + q];
        }
        __syncthreads();
        for (int kk = 0; kk < 32; kk++) {
            float a = attn[r * 260 + k0 + kk];
            float4 b0 = *(float4*)&Vs[kk * 132 + 4 * tx];
            float4 b1 = *(float4*)&Vs[kk * 132 + 64 + 4 * tx];
            acc0.x = fmaf(a, b0.x, acc0.x); acc0.y = fmaf(a, b0.y, acc0.y);
            acc0.z = fmaf(a, b0.z, acc0.z); acc0.w = fmaf(a, b0.w, acc0.w);
            acc1.x = fmaf(a, b1.x, acc1.x); acc1.y = fmaf(a, b1.y, acc1.y);
            acc1.z = fmaf(a, b1.z, acc1.z); acc1.w = fmaf(a, b1.w, acc1.w);
        }
    }
    float sm = reds[r][0] + reds[r][1] + reds[r][2] + reds[r][3];
    float rinv = 1.f / sm;
    acc0.x *= rinv; acc0.y *= rinv; acc0.z *= rinv; acc0.w *= rinv;
    acc1.x *= rinv; acc1.y *= rinv; acc1.z *= rinv; acc1.w *= rinv;
    int m = x0 + r;
    *(float4*)&out[b * TT * CC + m * CC + 4 * tx]      = acc0;
    *(float4*)&out[b * TT * CC + m * CC + 64 + 4 * tx] = acc1;
}

extern "C" void kernel_launch(void* const* d_in, const int* in_sizes, int n_in,
                              void* d_out, int out_size, void* d_ws, size_t ws_size,
                              hipStream_t stream) {
    const float* x    = (const float*)d_in[0];
    const int*   radj = (const int*)d_in[1];
    const int*   inxs = (const int*)d_in[2];
    const float* Wpf  = (const float*)d_in[3];
    const float* Wns  = (const float*)d_in[4];
    const float* Wv   = (const float*)d_in[5];
    const float* v_pf = (const float*)d_in[6];
    const float* g_pf = (const float*)d_in[7];
    const float* v_ns = (const float*)d_in[8];
    const float* g_ns = (const float*)d_in[9];
    float* out = (float*)d_out;

    float* ws = (float*)d_ws;
    float* pf = ws;                       // 1M floats
    float* ns = ws + (1u << 20);          // 1M
    float* vv = ws + 2u * (1u << 20);     // 1M
    float* G  = ws + 4u * (1u << 20);     // 2M
    float* S  = ws + 6u * (1u << 20);     // 2M

    proj_kernel<<<dim3(256, 3), 256, 0, stream>>>(x, Wpf, Wns, Wv, pf, ns, vv);
    gram_combined<<<dim3(4, 4, 64), 256, 0, stream>>>(pf, ns, inxs, v_ns, g_ns, G, S);
    logits_softmax_pv<<<dim3(16, 32), 256, 0, stream>>>(G, S, radj, v_pf, g_pf, vv, out);
}

// Round 5
// 129.752 us; speedup vs baseline: 1.4599x; 1.1524x over previous
//
#include <hip/hip_runtime.h>
#include <math.h>

// B=32, T=256, C=128, NEIGH=5, TOPK=4.
// proj_kernel: pf=norm(x@Wpf^T), ns=norm(x@Wns^T), v=x@Wv^T  (fp32, 64-row tiles)
// gram_mfma:   z&1==0 -> G[b]=pf@pf^T ; z&1==1 -> S[b]=Q@ns^T (Q gathered on the fly)
//              split-bf16 MFMA: A*B ~= Ah*Bh + Ah*Bl + Al*Bh  (err ~2^-17)
// fused:       rowmax(G) conv + S + mask -> softmax in LDS -> attn @ v

#define TT 256
#define CC 128

using bf16x8 = __attribute__((ext_vector_type(8))) short;
using f32x4  = __attribute__((ext_vector_type(4))) float;

__device__ __forceinline__ short bf_hi(float x) {
    unsigned u = __float_as_uint(x);
    return (short)((u + 0x7FFFu + ((u >> 16) & 1u)) >> 16);
}
__device__ __forceinline__ void bf_split(float x, short& h, short& l) {
    h = bf_hi(x);
    float hf = __uint_as_float(((unsigned)(unsigned short)h) << 16);
    l = bf_hi(x - hf);
}

// ---- proj: 64 rows/block, one matrix per blockIdx.y. out[r][j]=sum_k x[r][k]*W[j][k]
__global__ __launch_bounds__(256) void proj_kernel(
    const float* __restrict__ x,
    const float* __restrict__ W0, const float* __restrict__ W1, const float* __restrict__ W2,
    float* __restrict__ o0, float* __restrict__ o1, float* __restrict__ o2)
{
    __shared__ float xs[64][36];
    __shared__ float Ws[128][36];
    const int tid = threadIdx.x, ty = tid >> 4, tx = tid & 15;
    const int row0 = blockIdx.x * 64;
    const int m = blockIdx.y;
    const float* __restrict__ W = (m == 0) ? W0 : (m == 1) ? W1 : W2;
    float* __restrict__ o = (m == 0) ? o0 : (m == 1) ? o1 : o2;
    float acc[4][8] = {};

    for (int k0 = 0; k0 < CC; k0 += 32) {
        __syncthreads();
        for (int i = 0; i < 2; i++) {          // xs: 64x32 = 512 float4
            int flat = i * 256 + tid, r = flat >> 3, q = (flat & 7) * 4;
            *(float4*)&xs[r][q] = *(const float4*)&x[(row0 + r) * CC + k0 + q];
        }
        for (int i = 0; i < 4; i++) {          // Ws: 128x32 = 1024 float4
            int flat = i * 256 + tid, r = flat >> 3, q = (flat & 7) * 4;
            *(float4*)&Ws[r][q] = *(const float4*)&W[r * CC + k0 + q];
        }
        __syncthreads();
        for (int kq = 0; kq < 32; kq += 4) {
            float4 av[4], bv[8];
            for (int u = 0; u < 4; u++) av[u] = *(float4*)&xs[ty + 16 * u][kq];
            for (int w = 0; w < 8; w++) bv[w] = *(float4*)&Ws[tx + 16 * w][kq];
            for (int u = 0; u < 4; u++)
                for (int w = 0; w < 8; w++) {
                    acc[u][w] = fmaf(av[u].x, bv[w].x, acc[u][w]);
                    acc[u][w] = fmaf(av[u].y, bv[w].y, acc[u][w]);
                    acc[u][w] = fmaf(av[u].z, bv[w].z, acc[u][w]);
                    acc[u][w] = fmaf(av[u].w, bv[w].w, acc[u][w]);
                }
        }
    }
    for (int u = 0; u < 4; u++) {
        float inv = 1.f;
        if (m < 2) {
            float ss = 0.f;
            for (int w = 0; w < 8; w++) ss += acc[u][w] * acc[u][w];
            for (int off = 8; off; off >>= 1) ss += __shfl_xor(ss, off);
            inv = 1.f / fmaxf(sqrtf(ss), 1e-12f);
        }
        int row = row0 + ty + 16 * u;
        for (int w = 0; w < 8; w++)
            o[row * CC + tx + 16 * w] = acc[u][w] * inv;
    }
}

// ---- split-bf16 MFMA gram. z = b*2 + half. half=0: G=pf@pf^T. half=1: S=Q@ns^T.
// LDS bf16 tiles: row stride 40 shorts (80B, 16B-aligned frag reads).
__global__ __launch_bounds__(256, 4) void gram_mfma(
    const float* __restrict__ pf, const float* __restrict__ ns,
    const int* __restrict__ inxs, const float* __restrict__ v_ns,
    const float* __restrict__ g_ns, float* __restrict__ G, float* __restrict__ S)
{
    __shared__ short Ah[64 * 40], Al[64 * 40], Bh[64 * 40], Bl[64 * 40];
    const int tid = threadIdx.x;
    const int m0 = blockIdx.x * 64, n0 = blockIdx.y * 64;
    const int b = blockIdx.z >> 1, half = blockIdx.z & 1;
    const float* __restrict__ Pb = pf + b * TT * CC;
    const float* __restrict__ Nb = ns + b * TT * CC;
    const float* __restrict__ Bsrc = half ? Nb : Pb;

    float w0 = 0.f, w1 = 0.f, w2 = 0.f, w3 = 0.f;
    int4 id0 = {0, 0, 0, 0}, id1 = {0, 0, 0, 0};
    if (half) {
        float n2 = v_ns[0]*v_ns[0] + v_ns[1]*v_ns[1] + v_ns[2]*v_ns[2] + v_ns[3]*v_ns[3];
        float sc = g_ns[0] / sqrtf(n2);
        w0 = sc*v_ns[0]; w1 = sc*v_ns[1]; w2 = sc*v_ns[2]; w3 = sc*v_ns[3];
        id0 = *(const int4*)&inxs[(b * TT + m0 + (tid >> 3)) * 4];
        id1 = *(const int4*)&inxs[(b * TT + m0 + 32 + (tid >> 3)) * 4];
    }

    const int lane = tid & 63, wave = tid >> 6;
    const int wm = wave >> 1, wn = wave & 1;
    const int quad = lane >> 4, lr = lane & 15;
    f32x4 z4 = {0.f, 0.f, 0.f, 0.f};
    f32x4 acc[2][2] = {{z4, z4}, {z4, z4}};

    for (int k0 = 0; k0 < CC; k0 += 32) {
        __syncthreads();
        for (int i = 0; i < 2; i++) {
            int flat = i * 256 + tid, r = flat >> 3, q = (flat & 7) * 4;
            float4 a4;
            if (!half) {
                a4 = *(const float4*)&Pb[(m0 + r) * CC + k0 + q];
            } else {
                int4 id = i ? id1 : id0;
                float4 aa = *(const float4*)&Nb[id.x * CC + k0 + q];
                float4 ab = *(const float4*)&Nb[id.y * CC + k0 + q];
                float4 ac = *(const float4*)&Nb[id.z * CC + k0 + q];
                float4 ad = *(const float4*)&Nb[id.w * CC + k0 + q];
                a4.x = w0*aa.x + w1*ab.x + w2*ac.x + w3*ad.x;
                a4.y = w0*aa.y + w1*ab.y + w2*ac.y + w3*ad.y;
                a4.z = w0*aa.z + w1*ab.z + w2*ac.z + w3*ad.z;
                a4.w = w0*aa.w + w1*ab.w + w2*ac.w + w3*ad.w;
            }
            float4 b4 = *(const float4*)&Bsrc[(n0 + r) * CC + k0 + q];
            short4 h4, l4;
            bf_split(a4.x, h4.x, l4.x); bf_split(a4.y, h4.y, l4.y);
            bf_split(a4.z, h4.z, l4.z); bf_split(a4.w, h4.w, l4.w);
            *(short4*)&Ah[r * 40 + q] = h4; *(short4*)&Al[r * 40 + q] = l4;
            bf_split(b4.x, h4.x, l4.x); bf_split(b4.y, h4.y, l4.y);
            bf_split(b4.z, h4.z, l4.z); bf_split(b4.w, h4.w, l4.w);
            *(short4*)&Bh[r * 40 + q] = h4; *(short4*)&Bl[r * 40 + q] = l4;
        }
        __syncthreads();
        bf16x8 bh[2], bl[2];
        for (int tn = 0; tn < 2; tn++) {
            int br = (32 * wn + 16 * tn + lr) * 40 + quad * 8;
            bh[tn] = *(bf16x8*)&Bh[br];
            bl[tn] = *(bf16x8*)&Bl[br];
        }
        for (int tm = 0; tm < 2; tm++) {
            int ar = (32 * wm + 16 * tm + lr) * 40 + quad * 8;
            bf16x8 ah = *(bf16x8*)&Ah[ar];
            bf16x8 al = *(bf16x8*)&Al[ar];
            for (int tn = 0; tn < 2; tn++) {
                acc[tm][tn] = __builtin_amdgcn_mfma_f32_16x16x32_bf16(ah, bh[tn], acc[tm][tn], 0, 0, 0);
                acc[tm][tn] = __builtin_amdgcn_mfma_f32_16x16x32_bf16(ah, bl[tn], acc[tm][tn], 0, 0, 0);
                acc[tm][tn] = __builtin_amdgcn_mfma_f32_16x16x32_bf16(al, bh[tn], acc[tm][tn], 0, 0, 0);
            }
        }
    }
    float* __restrict__ Cb = (half ? S : G) + b * TT * TT;
    for (int tm = 0; tm < 2; tm++)
        for (int tn = 0; tn < 2; tn++) {
            int rb = m0 + 32 * wm + 16 * tm + quad * 4;
            int cb = n0 + 32 * wn + 16 * tn + lr;
            for (int reg = 0; reg < 4; reg++)
                Cb[(rb + reg) * TT + cb] = acc[tm][tn][reg];
        }
}

// ---- fused: logits (rowmax conv + S + mask) -> softmax -> attn@V.
// LDS overlay (floats): GS[0,5120) RM[5120,10320) AT[10320,14480)
//                       RD[14480,14544) RMx[14544,14608)
//                       phase2: VS[0,4224) PP[4224,12416)
#define GS_ 0
#define RM_ 5120
#define AT_ 10320
#define RD_ 14480
#define RMX_ 14544
#define VS_ 0
#define PP_ 4224
__global__ __launch_bounds__(256, 2) void fused_smax_pv(
    const float* __restrict__ G, const float* __restrict__ S,
    const int* __restrict__ radj, const float* __restrict__ v_pf,
    const float* __restrict__ g_pf, const float* __restrict__ V,
    float* __restrict__ out)
{
    __shared__ float lds[14608];
    const int tid = threadIdx.x;
    const int xt = blockIdx.x, b = blockIdx.y;
    const int x0 = xt * 16;
    const int rbase = min(max(x0 - 2, 0), TT - 5);
    for (int i = 0; i < 5; i++) {              // stage 20 G rows
        int flat = i * 256 + tid, ri = flat >> 6, q = (flat & 63) * 4;
        int r = min(rbase + ri, TT - 1);
        *(float4*)&lds[GS_ + ri * 256 + q] = *(const float4*)&G[b * TT * TT + r * TT + q];
    }
    float n2 = 0.f;
    for (int i = 0; i < 5; i++) n2 += v_pf[i] * v_pf[i];
    float sc = g_pf[0] / sqrtf(n2);
    float wpf[5];
    for (int i = 0; i < 5; i++) wpf[i] = sc * v_pf[i];
    __syncthreads();

    // phase 1a: windowed row max (per column y = tid)
    const int y = tid;
    const int sy = min(max(y - 2, 0), TT - 5);
    for (int i = 0; i < 20; i++) {
        const float* row = &lds[GS_ + i * 256 + sy];
        float mx = row[0];
        for (int j = 1; j < 5; j++) mx = fmaxf(mx, row[j]);
        lds[RM_ + i * 260 + y] = mx;           // same-thread read below: no barrier
    }
    // phase 1b: logits + softmax
    float lv[16];
    for (int xi = 0; xi < 16; xi++) {
        int sxr = min(max(x0 + xi - 2, 0), TT - 5) - rbase;
        float s = 0.f;
        for (int i = 0; i < 5; i++)
            s = fmaf(wpf[i], lds[RM_ + (sxr + i) * 260 + y], s);
        s += S[b * TT * TT + (x0 + xi) * TT + y];
        if (radj[(b * TT + x0 + xi) * TT + y] == 0) s += -1e22f;
        lv[xi] = s;
    }
    const int lane = tid & 63, wv = tid >> 6;
    for (int xi = 0; xi < 16; xi++) {
        float v = lv[xi];
        for (int o = 32; o; o >>= 1) v = fmaxf(v, __shfl_xor(v, o));
        if (lane == 0) lds[RMX_ + xi * 4 + wv] = v;
    }
    __syncthreads();
    for (int xi = 0; xi < 16; xi++) {
        float mx = fmaxf(fmaxf(lds[RMX_ + xi * 4], lds[RMX_ + xi * 4 + 1]),
                         fmaxf(lds[RMX_ + xi * 4 + 2], lds[RMX_ + xi * 4 + 3]));
        float e = __expf(lv[xi] - mx);
        lds[AT_ + xi * 260 + y] = e;           // raw; normalized in epilogue
        for (int o = 32; o; o >>= 1) e += __shfl_xor(e, o);
        if (lane == 0) lds[RD_ + xi * 4 + wv] = e;
    }
    // phase 2: attn @ V. thread = (tx: 8 cols, qt: 4 queries, w: 8-kk slice of chunk)
    const int tx = tid & 15, qt = (tid >> 4) & 3, w = tid >> 6;
    const float* __restrict__ Vb = V + b * TT * CC;
    float4 a0[4] = {}, a1[4] = {};
    for (int c = 0; c < 8; c++) {
        int kk0 = c * 32;
        __syncthreads();
        for (int i = 0; i < 4; i++) {
            int flat = i * 256 + tid, kk = flat >> 5, q = (flat & 31) * 4;
            *(float4*)&lds[VS_ + kk * 132 + q] = *(const float4*)&Vb[(kk0 + kk) * CC + q];
        }
        __syncthreads();
        for (int s = 0; s < 2; s++) {
            int kl = w * 8 + s * 4;
            float atv[4][4];
            for (int j = 0; j < 4; j++) {
                float4 t = *(float4*)&lds[AT_ + (qt * 4 + j) * 260 + kk0 + kl];
                atv[j][0] = t.x; atv[j][1] = t.y; atv[j][2] = t.z; atv[j][3] = t.w;
            }
            for (int kk = 0; kk < 4; kk++) {
                float4 v0 = *(float4*)&lds[VS_ + (kl + kk) * 132 + 8 * tx];
                float4 v1 = *(float4*)&lds[VS_ + (kl + kk) * 132 + 8 * tx + 4];
                for (int j = 0; j < 4; j++) {
                    float a = atv[j][kk];
                    a0[j].x = fmaf(a, v0.x, a0[j].x); a0[j].y = fmaf(a, v0.y, a0[j].y);
                    a0[j].z = fmaf(a, v0.z, a0[j].z); a0[j].w = fmaf(a, v0.w, a0[j].w);
                    a1[j].x = fmaf(a, v1.x, a1[j].x); a1[j].y = fmaf(a, v1.y, a1[j].y);
                    a1[j].z = fmaf(a, v1.z, a1[j].z); a1[j].w = fmaf(a, v1.w, a1[j].w);
                }
            }
        }
    }
    __syncthreads();                           // attn dead; PP may overlay it
    for (int j = 0; j < 4; j++) {
        *(float4*)&lds[PP_ + (w * 16 + qt * 4 + j) * 128 + 8 * tx]     = a0[j];
        *(float4*)&lds[PP_ + (w * 16 + qt * 4 + j) * 128 + 8 * tx + 4] = a1[j];
    }
    __syncthreads();
    const int q = tid >> 4, c0 = (tid & 15) * 8;
    float4 r0 = {0, 0, 0, 0}, r1 = {0, 0, 0, 0};
    for (int ww = 0; ww < 4; ww++) {
        float4 p0 = *(float4*)&lds[PP_ + (ww * 16 + q) * 128 + c0];
        float4 p1 = *(float4*)&lds[PP_ + (ww * 16 + q) * 128 + c0 + 4];
        r0.x += p0.x; r0.y += p0.y; r0.z += p0.z; r0.w += p0.w;
        r1.x += p1.x; r1.y += p1.y; r1.z += p1.z; r1.w += p1.w;
    }
    float sm = lds[RD_ + q * 4] + lds[RD_ + q * 4 + 1] + lds[RD_ + q * 4 + 2] + lds[RD_ + q * 4 + 3];
    float rinv = 1.f / sm;
    r0.x *= rinv; r0.y *= rinv; r0.z *= rinv; r0.w *= rinv;
    r1.x *= rinv; r1.y *= rinv; r1.z *= rinv; r1.w *= rinv;
    *(float4*)&out[b * TT * CC + (x0 + q) * CC + c0]     = r0;
    *(float4*)&out[b * TT * CC + (x0 + q) * CC + c0 + 4] = r1;
}

extern "C" void kernel_launch(void* const* d_in, const int* in_sizes, int n_in,
                              void* d_out, int out_size, void* d_ws, size_t ws_size,
                              hipStream_t stream) {
    const float* x    = (const float*)d_in[0];
    const int*   radj = (const int*)d_in[1];
    const int*   inxs = (const int*)d_in[2];
    const float* Wpf  = (const float*)d_in[3];
    const float* Wns  = (const float*)d_in[4];
    const float* Wv   = (const float*)d_in[5];
    const float* v_pf = (const float*)d_in[6];
    const float* g_pf = (const float*)d_in[7];
    const float* v_ns = (const float*)d_in[8];
    const float* g_ns = (const float*)d_in[9];
    float* out = (float*)d_out;

    float* ws = (float*)d_ws;
    float* pf = ws;                       // 1M floats
    float* ns = ws + (1u << 20);          // 1M
    float* vv = ws + 2u * (1u << 20);     // 1M
    float* G  = ws + 4u * (1u << 20);     // 2M
    float* S  = ws + 6u * (1u << 20);     // 2M

    proj_kernel<<<dim3(128, 3), 256, 0, stream>>>(x, Wpf, Wns, Wv, pf, ns, vv);
    gram_mfma<<<dim3(4, 4, 64), 256, 0, stream>>>(pf, ns, inxs, v_ns, g_ns, G, S);
    fused_smax_pv<<<dim3(16, 32), 256, 0, stream>>>(G, S, radj, v_pf, g_pf, vv, out);
}